// Round 12
// baseline (223.942 us; speedup 1.0000x reference)
//
#include <hip/hip_runtime.h>
#include <hip/hip_bf16.h>

#define D 512
#define NSEQ 2048
#define NB 8
#define QBLK 64
#define KVBLK 64
#define NTHREADS 512
#define NT (NSEQ / KVBLK)          // 32 kv tiles
#define ROWE 2056                  // subtiled layout: elems per 4-row group
#define BUFE (16 * ROWE)           // 65792 B per [64][512] bf16 buffer
#define SROWP 68                   // f32 row stride for Ss
#define PROWP 72                   // bf16 row stride for Ps

typedef __attribute__((ext_vector_type(8))) short bf16x8;
typedef __attribute__((ext_vector_type(4))) float f32x4;

static __device__ __forceinline__ unsigned short f2b(float f) {
  unsigned u = __builtin_bit_cast(unsigned, f);
  return (unsigned short)((u + 0x7FFFu + ((u >> 16) & 1u)) >> 16);
}

// ---------------- conv: fp32 B -> b16 [kv][d] (memory-bound, ~10us) ---------
__global__ __launch_bounds__(256) void conv_b16(const float* __restrict__ in,
                                                unsigned short* __restrict__ out) {
  size_t i = ((size_t)blockIdx.x * 256 + threadIdx.x) * 8;
  float4 v0 = *reinterpret_cast<const float4*>(in + i);
  float4 v1 = *reinterpret_cast<const float4*>(in + i + 4);
  bf16x8 h;
  h[0] = (short)f2b(v0.x); h[1] = (short)f2b(v0.y);
  h[2] = (short)f2b(v0.z); h[3] = (short)f2b(v0.w);
  h[4] = (short)f2b(v1.x); h[5] = (short)f2b(v1.y);
  h[6] = (short)f2b(v1.z); h[7] = (short)f2b(v1.w);
  *reinterpret_cast<bf16x8*>(out + i) = h;
}

// ---------------------------- v12 main kernel -------------------------------
// Base = v10 (164us verified). Two isolated changes:
//  1) K-operand in registers (kf[16], v6/v11-proven pattern + per-tile
//     prefetch drained by the existing tile-end vmcnt(0)) -> QK^T LDS reads
//     drop 384->256 b128/tile. Q stays in LDS; arch regs ~95 (no spill).
//  2) Softmax Ss reads were ~8-way bank-conflicted (float4: quad start =
//     4r+8c mod 32 -> 8 values). Strided-scalar reads (col = c+8j: bank =
//     4r+c+8j -> <=2-way, free); Ps written as strided u16 (2 lanes/bank).
//     P values and all consumer layouts unchanged.
// Bt/O^T path from r11 dropped (regressed for unexplained reasons).
// LDS: Bs 65792 + Qs 65792 + Ss 17408 + Ps 9216 + stats 768 = 158976 B.
__global__ __launch_bounds__(NTHREADS, 1)
void attn_v12(const float* __restrict__ A, const unsigned short* __restrict__ B16,
              float* __restrict__ Out) {
  __shared__ __align__(16) unsigned short Bs[BUFE];
  __shared__ __align__(16) unsigned short Qs[BUFE];
  __shared__ __align__(16) float Ss[QBLK * SROWP];
  __shared__ __align__(16) unsigned short Ps[QBLK * PROWP];
  __shared__ float mS[QBLK];
  __shared__ float lS[QBLK];
  __shared__ float aS[QBLK];

  const int tid  = threadIdx.x;
  const int wid  = tid >> 6;
  const int lane = tid & 63;
  const int l16  = lane & 15;
  const int g4   = lane >> 4;

  const int batch = blockIdx.x & 7;       // batch -> XCD (L2 locality for b panel)
  const int qt    = blockIdx.x >> 3;      // 0..31
  const int qbase = qt * QBLK;

  const float*          Ab   = A   + (size_t)batch * NSEQ * D;
  const unsigned short* Bb16 = B16 + (size_t)batch * NSEQ * D;
  float*                Ob   = Out + (size_t)batch * NSEQ * D;

  const float scale = 0.04419417382415922f;  // 1/sqrt(512)

  const int ki = wid & 3;    // wave's kv 16-tile for QK^T
  const int qp = wid >> 2;   // wave's q 32-half: tiles qp*2, qp*2+1

  // ---- stage Q into LDS (pre-scaled), subtiled layout (v10 verbatim) ----
  {
    const int q  = tid >> 3;
    const int dc = (tid & 7) * 64;
    const float* src = Ab + (size_t)(qbase + q) * D + dc;
    const int gbase = (q >> 2) * ROWE + (q & 3) * 16;
    #pragma unroll
    for (int j = 0; j < 8; ++j) {
      float4 v0 = *reinterpret_cast<const float4*>(src + j * 8);
      float4 v1 = *reinterpret_cast<const float4*>(src + j * 8 + 4);
      bf16x8 h;
      h[0] = (short)f2b(v0.x * scale); h[1] = (short)f2b(v0.y * scale);
      h[2] = (short)f2b(v0.z * scale); h[3] = (short)f2b(v0.w * scale);
      h[4] = (short)f2b(v1.x * scale); h[5] = (short)f2b(v1.y * scale);
      h[6] = (short)f2b(v1.z * scale); h[7] = (short)f2b(v1.w * scale);
      int d = dc + j * 8;
      *reinterpret_cast<bf16x8*>(&Qs[gbase + (d >> 4) * 64 + (d & 15)]) = h;
    }
  }
  if (tid < QBLK) { mS[tid] = -1e30f; lS[tid] = 0.f; }

  // ---- kf tile 0 from b16 [kv][d] (v6/v11-proven pattern) ----
  const unsigned short* kptr = Bb16 + (size_t)(ki * 16 + l16) * D + g4 * 8;
  bf16x8 kf[16];
  #pragma unroll
  for (int ks = 0; ks < 16; ++ks)
    kf[ks] = *reinterpret_cast<const bf16x8*>(kptr + ks * 32);

  f32x4 acc[4][4];
  #pragma unroll
  for (int mi = 0; mi < 4; ++mi)
    #pragma unroll
    for (int ni = 0; ni < 4; ++ni)
      acc[mi][ni] = (f32x4){0.f, 0.f, 0.f, 0.f};

  // ---- prologue: DMA tile 0 -> Bs (v10 verbatim) ----
  #pragma unroll
  for (int c = 0; c < 8; ++c) {
    int id = wid * 8 + c;
    int g = id >> 2, q = id & 3;
    const unsigned short* src = Bb16
        + (size_t)(g * 4 + ((lane >> 1) & 3)) * D
        + q * 128 + (lane >> 3) * 16 + (lane & 1) * 8;
    unsigned short* dst = &Bs[g * ROWE + q * 512];
    __builtin_amdgcn_global_load_lds(
        (const __attribute__((address_space(1))) void*)src,
        (__attribute__((address_space(3))) void*)dst, 16, 0, 0);
  }
  asm volatile("s_waitcnt vmcnt(0)" ::: "memory");
  asm volatile("s_waitcnt lgkmcnt(0)" ::: "memory");
  __builtin_amdgcn_s_barrier();

  const int qrb0 = ((qp * 2) * 4 + (l16 >> 2)) * ROWE + (l16 & 3) * 16 + (g4 & 1) * 8;
  const int qrb1 = qrb0 + 4 * ROWE;

  for (int kt = 0; kt < NT; ++kt) {
    // ---- QK^T: Q from Qs (b128), K from kf regs; 2 S-tiles/wave ----
    {
      f32x4 s0 = {0.f, 0.f, 0.f, 0.f};
      f32x4 s1 = {0.f, 0.f, 0.f, 0.f};
      __builtin_amdgcn_s_setprio(1);
      #pragma unroll
      for (int ks = 0; ks < 16; ++ks) {
        const int ro = (ks * 2 + (g4 >> 1)) * 64;
        const bf16x8 q0 = *reinterpret_cast<const bf16x8*>(&Qs[qrb0 + ro]);
        const bf16x8 q1 = *reinterpret_cast<const bf16x8*>(&Qs[qrb1 + ro]);
        s0 = __builtin_amdgcn_mfma_f32_16x16x32_bf16(q0, kf[ks], s0, 0, 0, 0);
        s1 = __builtin_amdgcn_mfma_f32_16x16x32_bf16(q1, kf[ks], s1, 0, 0, 0);
      }
      __builtin_amdgcn_s_setprio(0);
      #pragma unroll
      for (int r = 0; r < 4; ++r) {
        Ss[(qp * 32 + g4 * 4 + r) * SROWP + ki * 16 + l16]      = s0[r];
        Ss[(qp * 32 + 16 + g4 * 4 + r) * SROWP + ki * 16 + l16] = s1[r];
      }
    }
    asm volatile("s_waitcnt lgkmcnt(0)" ::: "memory");
    __builtin_amdgcn_s_barrier();

    // ---- kf prefetch kt+1 (drained by tile-end vmcnt(0)) ----
    if (kt + 1 < NT) {
      kptr += (size_t)KVBLK * D;
      #pragma unroll
      for (int ks = 0; ks < 16; ++ks)
        kf[ks] = *reinterpret_cast<const bf16x8*>(kptr + ks * 32);
    }

    // ---- online softmax: 8 lanes/row, STRIDED cols (conflict-free) ----
    {
      int row = wid * 8 + (lane >> 3);
      int c   = lane & 7;
      float sv[8];
      float mloc = -1e30f;
      #pragma unroll
      for (int j = 0; j < 8; ++j) {
        sv[j] = Ss[row * SROWP + c + 8 * j];   // bank = 4r+c+8j -> <=2-way
        mloc = fmaxf(mloc, sv[j]);
      }
      #pragma unroll
      for (int off = 1; off < 8; off <<= 1)
        mloc = fmaxf(mloc, __shfl_xor(mloc, off));
      float mold = mS[row];
      float mnew = fmaxf(mold, mloc);
      float al = __expf(mold - mnew);
      float psum = 0.f;
      #pragma unroll
      for (int j = 0; j < 8; ++j) {
        float p = __expf(sv[j] - mnew);
        psum += p;
        Ps[row * PROWP + c + 8 * j] = f2b(p);  // strided u16: 2 lanes/bank
      }
      #pragma unroll
      for (int off = 1; off < 8; off <<= 1)
        psum += __shfl_xor(psum, off);
      if (c == 0) {
        mS[row] = mnew;
        lS[row] = lS[row] * al + psum;
        aS[row] = al;
      }
    }
    asm volatile("s_waitcnt lgkmcnt(0)" ::: "memory");
    __builtin_amdgcn_s_barrier();

    // ---- rescale acc + PV (v10 verbatim): wave owns d-slice [wid*64,+64) ----
    {
      #pragma unroll
      for (int mi = 0; mi < 4; ++mi)
        #pragma unroll
        for (int r = 0; r < 4; ++r) {
          float a = aS[mi * 16 + g4 * 4 + r];
          #pragma unroll
          for (int ni = 0; ni < 4; ++ni)
            acc[mi][ni][r] *= a;
        }

      const unsigned short* Bc = &Bs[0];
      __builtin_amdgcn_s_setprio(1);
      #pragma unroll
      for (int ks = 0; ks < 2; ++ks) {
        bf16x8 pf[4];
        #pragma unroll
        for (int mi = 0; mi < 4; ++mi)
          pf[mi] = *reinterpret_cast<const bf16x8*>(
              &Ps[(mi * 16 + l16) * PROWP + ks * 32 + g4 * 8]);
        #pragma unroll
        for (int ni = 0; ni < 4; ++ni) {
          bf16x8 vv;
          #pragma unroll
          for (int j = 0; j < 8; ++j)
            vv[j] = (short)Bc[(ks * 8 + g4 * 2 + (j >> 2)) * ROWE
                              + (wid * 4 + ni) * 64 + (j & 3) * 16 + l16];
          #pragma unroll
          for (int mi = 0; mi < 4; ++mi)
            acc[mi][ni] = __builtin_amdgcn_mfma_f32_16x16x32_bf16(pf[mi], vv, acc[mi][ni], 0, 0, 0);
        }
      }
      __builtin_amdgcn_s_setprio(0);
    }

    // ---- all PV reads of Bs done across the block -> safe to overwrite ----
    __builtin_amdgcn_s_barrier();
    if (kt + 1 < NT) {
      const unsigned short* Bt = Bb16 + (size_t)(kt + 1) * KVBLK * D;
      #pragma unroll
      for (int c = 0; c < 8; ++c) {
        int id = wid * 8 + c;
        int g = id >> 2, q = id & 3;
        const unsigned short* src = Bt
            + (size_t)(g * 4 + ((lane >> 1) & 3)) * D
            + q * 128 + (lane >> 3) * 16 + (lane & 1) * 8;
        unsigned short* dst = &Bs[g * ROWE + q * 512];
        __builtin_amdgcn_global_load_lds(
            (const __attribute__((address_space(1))) void*)src,
            (__attribute__((address_space(3))) void*)dst, 16, 0, 0);
      }
      asm volatile("s_waitcnt vmcnt(0)" ::: "memory");  // drains Bs DMA + kf prefetch
    }
    __builtin_amdgcn_s_barrier();     // Bs(kt+1) ready for all waves
  }

  // ---- epilogue: out = acc / l + a (v10 verbatim) ----
  #pragma unroll
  for (int mi = 0; mi < 4; ++mi)
    #pragma unroll
    for (int r = 0; r < 4; ++r) {
      float rl = 1.0f / lS[mi * 16 + g4 * 4 + r];
      #pragma unroll
      for (int ni = 0; ni < 4; ++ni) {
        int q = qbase + mi * 16 + g4 * 4 + r;
        int d = wid * 64 + ni * 16 + l16;
        size_t off = (size_t)q * D + d;
        Ob[off] = acc[mi][ni][r] * rl + Ab[off];
      }
    }
}

// ---------- fallback: in-kernel convert staging (no workspace) --------------
#define FQBLK 32
#define FSROWP (64 + 4)
#define FPROWP (64 + 8)
__global__ __launch_bounds__(NTHREADS, 2)
void attn_fb(const float* __restrict__ A, const float* __restrict__ B32,
             float* __restrict__ Out) {
  __shared__ __align__(16) unsigned short Bs[BUFE];
  __shared__ float Ss[FQBLK * FSROWP];
  __shared__ unsigned short Ps[FQBLK * FPROWP];
  __shared__ float mS[FQBLK];
  __shared__ float lS[FQBLK];
  __shared__ float aS[FQBLK];

  const int tid  = threadIdx.x;
  const int wid  = tid >> 6;
  const int lane = tid & 63;
  const int l16  = lane & 15;
  const int g4   = lane >> 4;

  const int batch = blockIdx.x & 7;
  const int qt    = blockIdx.x >> 3;
  const int qbase = qt * FQBLK;

  const float* Ab   = A   + (size_t)batch * NSEQ * D;
  const float* Bb32 = B32 + (size_t)batch * NSEQ * D;
  float*       Ob   = Out + (size_t)batch * NSEQ * D;

  const float scale = 0.04419417382415922f;

  const int qi = wid >> 2;
  const int ki = wid & 3;

  const float* Arow = Ab + (size_t)(qbase + qi * 16 + l16) * D;
  bf16x8 qf[16];
  #pragma unroll
  for (int ks = 0; ks < 16; ++ks) {
    int d0 = ks * 32 + g4 * 8;
    float4 v0 = *reinterpret_cast<const float4*>(Arow + d0);
    float4 v1 = *reinterpret_cast<const float4*>(Arow + d0 + 4);
    bf16x8 f;
    f[0] = (short)f2b(v0.x * scale); f[1] = (short)f2b(v0.y * scale);
    f[2] = (short)f2b(v0.z * scale); f[3] = (short)f2b(v0.w * scale);
    f[4] = (short)f2b(v1.x * scale); f[5] = (short)f2b(v1.y * scale);
    f[6] = (short)f2b(v1.z * scale); f[7] = (short)f2b(v1.w * scale);
    qf[ks] = f;
  }
  if (tid < FQBLK) { mS[tid] = -1e30f; lS[tid] = 0.f; }

  f32x4 acc[2][4];
  #pragma unroll
  for (int mi = 0; mi < 2; ++mi)
    #pragma unroll
    for (int ni = 0; ni < 4; ++ni)
      acc[mi][ni] = (f32x4){0.f, 0.f, 0.f, 0.f};

  for (int kt = 0; kt < NT; ++kt) {
    __builtin_amdgcn_s_barrier();
    const float* Bt2 = Bb32 + (size_t)kt * KVBLK * D;
    #pragma unroll
    for (int c = 0; c < 8; ++c) {
      int id = wid * 8 + c;
      int g = id >> 2, q = id & 3;
      int kv = g * 4 + ((lane >> 1) & 3);
      int d  = q * 128 + (lane >> 3) * 16 + (lane & 1) * 8;
      const float* s = Bt2 + (size_t)kv * D + d;
      float4 v0 = *reinterpret_cast<const float4*>(s);
      float4 v1 = *reinterpret_cast<const float4*>(s + 4);
      bf16x8 h;
      h[0] = (short)f2b(v0.x); h[1] = (short)f2b(v0.y);
      h[2] = (short)f2b(v0.z); h[3] = (short)f2b(v0.w);
      h[4] = (short)f2b(v1.x); h[5] = (short)f2b(v1.y);
      h[6] = (short)f2b(v1.z); h[7] = (short)f2b(v1.w);
      *reinterpret_cast<bf16x8*>(&Bs[g * ROWE + q * 512 + lane * 8]) = h;
    }
    asm volatile("s_waitcnt lgkmcnt(0)" ::: "memory");
    __builtin_amdgcn_s_barrier();

    {
      f32x4 s = {0.f, 0.f, 0.f, 0.f};
      const int bbase = (ki * 4 + (l16 >> 2)) * ROWE + (l16 & 3) * 16 + (g4 & 1) * 8;
      #pragma unroll
      for (int ks = 0; ks < 16; ++ks) {
        const bf16x8 bf = *reinterpret_cast<const bf16x8*>(
            &Bs[bbase + (ks * 2 + (g4 >> 1)) * 64]);
        s = __builtin_amdgcn_mfma_f32_16x16x32_bf16(qf[ks], bf, s, 0, 0, 0);
      }
      #pragma unroll
      for (int r = 0; r < 4; ++r)
        Ss[(qi * 16 + g4 * 4 + r) * FSROWP + ki * 16 + l16] = s[r];
    }
    asm volatile("s_waitcnt lgkmcnt(0)" ::: "memory");
    __builtin_amdgcn_s_barrier();

    {
      int row = wid * 4 + g4;
      float sv[4];
      float mloc = -1e30f;
      #pragma unroll
      for (int j = 0; j < 4; ++j) {
        sv[j] = Ss[row * FSROWP + l16 + 16 * j];
        mloc = fmaxf(mloc, sv[j]);
      }
      #pragma unroll
      for (int off = 1; off < 16; off <<= 1)
        mloc = fmaxf(mloc, __shfl_xor(mloc, off));
      float mold = mS[row];
      float mnew = fmaxf(mold, mloc);
      float al = __expf(mold - mnew);
      float psum = 0.f;
      #pragma unroll
      for (int j = 0; j < 4; ++j) {
        float p = __expf(sv[j] - mnew);
        psum += p;
        Ps[row * FPROWP + l16 + 16 * j] = f2b(p);
      }
      #pragma unroll
      for (int off = 1; off < 16; off <<= 1)
        psum += __shfl_xor(psum, off);
      if (l16 == 0) {
        mS[row] = mnew;
        lS[row] = lS[row] * al + psum;
        aS[row] = al;
      }
    }
    asm volatile("s_waitcnt lgkmcnt(0)" ::: "memory");
    __builtin_amdgcn_s_barrier();

    {
      #pragma unroll
      for (int mi = 0; mi < 2; ++mi)
        #pragma unroll
        for (int r = 0; r < 4; ++r) {
          float a = aS[mi * 16 + g4 * 4 + r];
          #pragma unroll
          for (int ni = 0; ni < 4; ++ni)
            acc[mi][ni][r] *= a;
        }

      #pragma unroll
      for (int ks = 0; ks < 2; ++ks) {
        bf16x8 pf[2];
        #pragma unroll
        for (int mi = 0; mi < 2; ++mi)
          pf[mi] = *reinterpret_cast<const bf16x8*>(
              &Ps[(mi * 16 + l16) * FPROWP + ks * 32 + g4 * 8]);
        #pragma unroll
        for (int ni = 0; ni < 4; ++ni) {
          bf16x8 vv;
          #pragma unroll
          for (int j = 0; j < 8; ++j)
            vv[j] = (short)Bs[(ks * 8 + g4 * 2 + (j >> 2)) * ROWE
                              + (wid * 4 + ni) * 64 + (j & 3) * 16 + l16];
          #pragma unroll
          for (int mi = 0; mi < 2; ++mi)
            acc[mi][ni] = __builtin_amdgcn_mfma_f32_16x16x32_bf16(pf[mi], vv, acc[mi][ni], 0, 0, 0);
        }
      }
    }
  }

  #pragma unroll
  for (int mi = 0; mi < 2; ++mi)
    #pragma unroll
    for (int r = 0; r < 4; ++r) {
      float rl = 1.0f / lS[mi * 16 + g4 * 4 + r];
      #pragma unroll
      for (int ni = 0; ni < 4; ++ni) {
        int q = qbase + mi * 16 + g4 * 4 + r;
        int d = wid * 64 + ni * 16 + l16;
        size_t off = (size_t)q * D + d;
        Ob[off] = acc[mi][ni][r] * rl + Ab[off];
      }
    }
}

extern "C" void kernel_launch(void* const* d_in, const int* in_sizes, int n_in,
                              void* d_out, int out_size, void* d_ws, size_t ws_size,
                              hipStream_t stream) {
  const float* a = (const float*)d_in[0];
  const float* b = (const float*)d_in[1];
  float* out = (float*)d_out;
  const size_t need = (size_t)NB * NSEQ * D * sizeof(unsigned short);  // 16 MB
  dim3 block(NTHREADS);
  if (ws_size >= need) {
    unsigned short* b16 = (unsigned short*)d_ws;
    conv_b16<<<4096, 256, 0, stream>>>(b, b16);
    dim3 grid(NB * (NSEQ / QBLK));            // 256 blocks = 1 per CU
    attn_v12<<<grid, block, 0, stream>>>(a, b16, out);
  } else {
    dim3 grid(NB * (NSEQ / FQBLK));
    attn_fb<<<grid, block, 0, stream>>>(a, b, out);
  }
}

// Round 13
// 169.443 us; speedup vs baseline: 1.3216x; 1.3216x over previous
//
#include <hip/hip_runtime.h>
#include <hip/hip_bf16.h>

#define D 512
#define NSEQ 2048
#define NB 8
#define QBLK 64
#define KVBLK 64
#define NTHREADS 512
#define NT (NSEQ / KVBLK)          // 32 kv tiles
#define ROWE 2056                  // Bs subtiled layout: elems per 4-kv-row group
#define BUFE (16 * ROWE)           // 65792 B Bs buffer
#define SROWP 68                   // f32 row stride for Ss
#define PROWP 72                   // bf16 row stride for Ps
#define CROWP 68                   // conv transpose tile stride (u16)

typedef __attribute__((ext_vector_type(8))) short bf16x8;
typedef __attribute__((ext_vector_type(4))) float f32x4;
typedef __attribute__((ext_vector_type(4))) unsigned short u16x4;

static __device__ __forceinline__ unsigned short f2b(float f) {
  unsigned u = __builtin_bit_cast(unsigned, f);
  return (unsigned short)((u + 0x7FFFu + ((u >> 16) & 1u)) >> 16);
}

// ------- conv: fp32 B -> b16 [kv][d] AND bT [d][kv] (r11-refcheck'd) --------
__global__ __launch_bounds__(256) void conv_dual(const float* __restrict__ in,
                                                 unsigned short* __restrict__ b16,
                                                 unsigned short* __restrict__ bT) {
  __shared__ unsigned short tile[64 * CROWP];
  const int bid = blockIdx.x;
  const int batch = bid >> 8;
  const int rem = bid & 255;
  const int kvt = rem >> 3;
  const int dt  = rem & 7;
  const int t = threadIdx.x;
  const int r = t >> 2;
  const int c = (t & 3) * 16;

  const float* src = in + ((size_t)batch * NSEQ + kvt * 64 + r) * D + dt * 64 + c;
  unsigned short* o16 = b16 + ((size_t)batch * NSEQ + kvt * 64 + r) * D + dt * 64 + c;

  float4 v0 = *reinterpret_cast<const float4*>(src);
  float4 v1 = *reinterpret_cast<const float4*>(src + 4);
  float4 v2 = *reinterpret_cast<const float4*>(src + 8);
  float4 v3 = *reinterpret_cast<const float4*>(src + 12);
  bf16x8 h0, h1;
  h0[0] = (short)f2b(v0.x); h0[1] = (short)f2b(v0.y);
  h0[2] = (short)f2b(v0.z); h0[3] = (short)f2b(v0.w);
  h0[4] = (short)f2b(v1.x); h0[5] = (short)f2b(v1.y);
  h0[6] = (short)f2b(v1.z); h0[7] = (short)f2b(v1.w);
  h1[0] = (short)f2b(v2.x); h1[1] = (short)f2b(v2.y);
  h1[2] = (short)f2b(v2.z); h1[3] = (short)f2b(v2.w);
  h1[4] = (short)f2b(v3.x); h1[5] = (short)f2b(v3.y);
  h1[6] = (short)f2b(v3.z); h1[7] = (short)f2b(v3.w);
  *reinterpret_cast<bf16x8*>(o16)     = h0;
  *reinterpret_cast<bf16x8*>(o16 + 8) = h1;
  #pragma unroll
  for (int i = 0; i < 4; ++i) {
    u16x4 w;
    w[0] = (unsigned short)((i < 2 ? h0 : h1)[(i & 1) * 4 + 0]);
    w[1] = (unsigned short)((i < 2 ? h0 : h1)[(i & 1) * 4 + 1]);
    w[2] = (unsigned short)((i < 2 ? h0 : h1)[(i & 1) * 4 + 2]);
    w[3] = (unsigned short)((i < 2 ? h0 : h1)[(i & 1) * 4 + 3]);
    *reinterpret_cast<u16x4*>(&tile[r * CROWP + c + i * 4]) = w;
  }
  __syncthreads();

  const int w  = t >> 6;
  const int dr = t & 63;
  unsigned short* oT = bT + (size_t)batch * D * NSEQ
                          + (size_t)(dt * 64 + dr) * NSEQ + kvt * 64 + w * 16;
  unsigned short g[16];
  #pragma unroll
  for (int i = 0; i < 16; ++i)
    g[i] = tile[(w * 16 + i) * CROWP + dr];
  bf16x8 p0, p1;
  #pragma unroll
  for (int i = 0; i < 8; ++i) { p0[i] = (short)g[i]; p1[i] = (short)g[8 + i]; }
  *reinterpret_cast<bf16x8*>(oT)     = p0;
  *reinterpret_cast<bf16x8*>(oT + 8) = p1;
}

// ---------------------------- v13 main kernel -------------------------------
// kf-from-global REFUTED (r6/r11/r12: scattered 16-line loads, +40-190us).
// v13 = v10 skeleton + only verified pieces:
//  - Q in regs (qf[16], v4/v5-verified; wave remap qi=wid>>1, kp=wid&1 ->
//    1 q-tile x 2 kv-tiles/wave): QK^T = 2 b128 per 2 MFMA, 256 b128/tile.
//  - PV via O^T = V^T*P^T from swizzled Bt (r11-refcheck'd): 16 b128/wave
//    replaces 64-u16 gather. Dropping Qs makes Bs+Bt fit:
//    65792 + 65536 + 17408 + 9216 + 768 = 158720 B.
//  - strided softmax (r12-refcheck'd, conflict-free).
__global__ __launch_bounds__(NTHREADS, 1)
void attn_v13(const float* __restrict__ A, const unsigned short* __restrict__ B16,
              const unsigned short* __restrict__ T16, float* __restrict__ Out) {
  __shared__ __align__(16) unsigned short Bs[BUFE];          // [kv][d] subtiled
  __shared__ __align__(16) unsigned short Bt[D * KVBLK];     // [d][kv] swizzled
  __shared__ __align__(16) float Ss[QBLK * SROWP];
  __shared__ __align__(16) unsigned short Ps[QBLK * PROWP];
  __shared__ float mS[QBLK];
  __shared__ float lS[QBLK];
  __shared__ float aS[QBLK];

  const int tid  = threadIdx.x;
  const int wid  = tid >> 6;
  const int lane = tid & 63;
  const int l16  = lane & 15;
  const int g4   = lane >> 4;

  const int batch = blockIdx.x & 7;       // batch -> XCD (L2 locality)
  const int qt    = blockIdx.x >> 3;      // 0..31
  const int qbase = qt * QBLK;

  const float*          Ab = A   + (size_t)batch * NSEQ * D;
  const unsigned short* Kb = B16 + (size_t)batch * NSEQ * D;
  const unsigned short* Tb = T16 + (size_t)batch * D * NSEQ;
  float*                Ob = Out + (size_t)batch * NSEQ * D;

  const float scale = 0.04419417382415922f;  // 1/sqrt(512)

  const int qi = wid >> 1;   // wave's q 16-tile (0..3)
  const int kp = wid & 1;    // wave's kv pair: kv-tiles kp*2, kp*2+1

  // ---- Q tile into registers (pre-scaled), v4/v5-verified pattern ----
  const float* Arow = Ab + (size_t)(qbase + qi * 16 + l16) * D;
  bf16x8 qf[16];
  #pragma unroll
  for (int ks = 0; ks < 16; ++ks) {
    int d0 = ks * 32 + g4 * 8;
    float4 v0 = *reinterpret_cast<const float4*>(Arow + d0);
    float4 v1 = *reinterpret_cast<const float4*>(Arow + d0 + 4);
    bf16x8 f;
    f[0] = (short)f2b(v0.x * scale); f[1] = (short)f2b(v0.y * scale);
    f[2] = (short)f2b(v0.z * scale); f[3] = (short)f2b(v0.w * scale);
    f[4] = (short)f2b(v1.x * scale); f[5] = (short)f2b(v1.y * scale);
    f[6] = (short)f2b(v1.z * scale); f[7] = (short)f2b(v1.w * scale);
    qf[ks] = f;
  }
  if (tid < QBLK) { mS[tid] = -1e30f; lS[tid] = 0.f; }

  f32x4 acc[4][4];   // O^T: acc[mi][ni], row d = wid*64+ni*16+l16? (r11 layout)
  #pragma unroll
  for (int mi = 0; mi < 4; ++mi)
    #pragma unroll
    for (int ni = 0; ni < 4; ++ni)
      acc[mi][ni] = (f32x4){0.f, 0.f, 0.f, 0.f};

  // ---- prologue: DMA Bs tile 0 (v10 pattern) + Bt tile 0 (r11 pattern) ----
  #pragma unroll
  for (int c = 0; c < 8; ++c) {
    int id = wid * 8 + c;
    int g = id >> 2, q = id & 3;
    const unsigned short* src = Kb
        + (size_t)(g * 4 + ((lane >> 1) & 3)) * D
        + q * 128 + (lane >> 3) * 16 + (lane & 1) * 8;
    unsigned short* dst = &Bs[g * ROWE + q * 512];
    __builtin_amdgcn_global_load_lds(
        (const __attribute__((address_space(1))) void*)src,
        (__attribute__((address_space(3))) void*)dst, 16, 0, 0);
  }
  #pragma unroll
  for (int c = 0; c < 8; ++c) {
    int drow = wid * 64 + c * 8 + (lane >> 3);
    int chunk = (lane & 7) ^ ((lane >> 3) & 7);
    const unsigned short* src = Tb + (size_t)drow * NSEQ + chunk * 8;
    unsigned short* dst = (unsigned short*)&Bt[(wid * 64 + c * 8) * KVBLK];
    __builtin_amdgcn_global_load_lds(
        (const __attribute__((address_space(1))) void*)src,
        (__attribute__((address_space(3))) void*)dst, 16, 0, 0);
  }
  asm volatile("s_waitcnt vmcnt(0)" ::: "memory");
  asm volatile("s_waitcnt lgkmcnt(0)" ::: "memory");
  __builtin_amdgcn_s_barrier();

  const int bbase0 = ((kp * 2) * 4 + (l16 >> 2)) * ROWE + (l16 & 3) * 16 + (g4 & 1) * 8;
  const int bbase1 = bbase0 + 4 * ROWE;   // next kv 16-tile (+16 kv rows)

  for (int kt = 0; kt < NT; ++kt) {
    // ---- QK^T: Q from regs, B from Bs (b128); 2 kv-tiles per wave ----
    {
      f32x4 s0 = {0.f, 0.f, 0.f, 0.f};
      f32x4 s1 = {0.f, 0.f, 0.f, 0.f};
      __builtin_amdgcn_s_setprio(1);
      #pragma unroll
      for (int ks = 0; ks < 16; ++ks) {
        const int ro = (ks * 2 + (g4 >> 1)) * 64;
        const bf16x8 b0 = *reinterpret_cast<const bf16x8*>(&Bs[bbase0 + ro]);
        const bf16x8 b1 = *reinterpret_cast<const bf16x8*>(&Bs[bbase1 + ro]);
        s0 = __builtin_amdgcn_mfma_f32_16x16x32_bf16(qf[ks], b0, s0, 0, 0, 0);
        s1 = __builtin_amdgcn_mfma_f32_16x16x32_bf16(qf[ks], b1, s1, 0, 0, 0);
      }
      __builtin_amdgcn_s_setprio(0);
      #pragma unroll
      for (int r = 0; r < 4; ++r) {
        Ss[(qi * 16 + g4 * 4 + r) * SROWP + (kp * 2) * 16 + l16]     = s0[r];
        Ss[(qi * 16 + g4 * 4 + r) * SROWP + (kp * 2 + 1) * 16 + l16] = s1[r];
      }
    }
    asm volatile("s_waitcnt lgkmcnt(0)" ::: "memory");
    __builtin_amdgcn_s_barrier();

    // ---- online softmax: 8 lanes/row, strided cols (r12-verified) ----
    {
      int row = wid * 8 + (lane >> 3);
      int c   = lane & 7;
      float sv[8];
      float mloc = -1e30f;
      #pragma unroll
      for (int j = 0; j < 8; ++j) {
        sv[j] = Ss[row * SROWP + c + 8 * j];   // bank = 4r+c+8j -> <=2-way
        mloc = fmaxf(mloc, sv[j]);
      }
      #pragma unroll
      for (int off = 1; off < 8; off <<= 1)
        mloc = fmaxf(mloc, __shfl_xor(mloc, off));
      float mold = mS[row];
      float mnew = fmaxf(mold, mloc);
      float al = __expf(mold - mnew);
      float psum = 0.f;
      #pragma unroll
      for (int j = 0; j < 8; ++j) {
        float p = __expf(sv[j] - mnew);
        psum += p;
        Ps[row * PROWP + c + 8 * j] = f2b(p);  // strided u16: 2 lanes/bank
      }
      #pragma unroll
      for (int off = 1; off < 8; off <<= 1)
        psum += __shfl_xor(psum, off);
      if (c == 0) {
        mS[row] = mnew;
        lS[row] = lS[row] * al + psum;
        aS[row] = al;
      }
    }
    asm volatile("s_waitcnt lgkmcnt(0)" ::: "memory");
    __builtin_amdgcn_s_barrier();

    // ---- rescale (col = q = l16) + PV: O^T += V^T * P^T (r11 verbatim) ----
    {
      #pragma unroll
      for (int mi = 0; mi < 4; ++mi) {
        float a = aS[mi * 16 + l16];
        #pragma unroll
        for (int ni = 0; ni < 4; ++ni)
          #pragma unroll
          for (int r = 0; r < 4; ++r)
            acc[mi][ni][r] *= a;
      }

      const char* Bc = (const char*)&Bt[0];
      __builtin_amdgcn_s_setprio(1);
      #pragma unroll
      for (int ks = 0; ks < 2; ++ks) {
        bf16x8 pf[4];
        #pragma unroll
        for (int mi = 0; mi < 4; ++mi)
          pf[mi] = *reinterpret_cast<const bf16x8*>(
              &Ps[(mi * 16 + l16) * PROWP + ks * 32 + g4 * 8]);
        #pragma unroll
        for (int ni = 0; ni < 4; ++ni) {
          int row = wid * 64 + ni * 16 + l16;
          int swz = (ks * 4 + g4) ^ (l16 & 7);
          const bf16x8 vf = *reinterpret_cast<const bf16x8*>(Bc + row * 128 + swz * 16);
          #pragma unroll
          for (int mi = 0; mi < 4; ++mi)
            acc[mi][ni] = __builtin_amdgcn_mfma_f32_16x16x32_bf16(vf, pf[mi], acc[mi][ni], 0, 0, 0);
        }
      }
      __builtin_amdgcn_s_setprio(0);
    }

    // ---- all reads of Bs/Bt done -> stage kt+1 into both, drain, barrier ----
    asm volatile("s_waitcnt lgkmcnt(0)" ::: "memory");
    __builtin_amdgcn_s_barrier();
    if (kt + 1 < NT) {
      const unsigned short* Kt = Kb + (size_t)(kt + 1) * KVBLK * D;
      #pragma unroll
      for (int c = 0; c < 8; ++c) {
        int id = wid * 8 + c;
        int g = id >> 2, q = id & 3;
        const unsigned short* src = Kt
            + (size_t)(g * 4 + ((lane >> 1) & 3)) * D
            + q * 128 + (lane >> 3) * 16 + (lane & 1) * 8;
        unsigned short* dst = &Bs[g * ROWE + q * 512];
        __builtin_amdgcn_global_load_lds(
            (const __attribute__((address_space(1))) void*)src,
            (__attribute__((address_space(3))) void*)dst, 16, 0, 0);
      }
      #pragma unroll
      for (int c = 0; c < 8; ++c) {
        int drow = wid * 64 + c * 8 + (lane >> 3);
        int chunk = (lane & 7) ^ ((lane >> 3) & 7);
        const unsigned short* src = Tb + (size_t)drow * NSEQ + (kt + 1) * KVBLK + chunk * 8;
        unsigned short* dst = (unsigned short*)&Bt[(wid * 64 + c * 8) * KVBLK];
        __builtin_amdgcn_global_load_lds(
            (const __attribute__((address_space(1))) void*)src,
            (__attribute__((address_space(3))) void*)dst, 16, 0, 0);
      }
      asm volatile("s_waitcnt vmcnt(0)" ::: "memory");
    }
    __builtin_amdgcn_s_barrier();
  }

  // ---- epilogue: Out[q][d] = accT/l + A[q][d] (r11 verbatim) ----
  #pragma unroll
  for (int mi = 0; mi < 4; ++mi) {
    float rl = 1.0f / lS[mi * 16 + l16];
    int q = qbase + mi * 16 + l16;
    #pragma unroll
    for (int ni = 0; ni < 4; ++ni) {
      int d = wid * 64 + ni * 16 + g4 * 4;
      const float4 av = *reinterpret_cast<const float4*>(Ab + (size_t)q * D + d);
      float4 o;
      o.x = acc[mi][ni][0] * rl + av.x;
      o.y = acc[mi][ni][1] * rl + av.y;
      o.z = acc[mi][ni][2] * rl + av.z;
      o.w = acc[mi][ni][3] * rl + av.w;
      *reinterpret_cast<float4*>(Ob + (size_t)q * D + d) = o;
    }
  }
}

// ---------- fallback: in-kernel convert staging (no workspace) --------------
#define FQBLK 32
#define FSROWP (64 + 4)
#define FPROWP (64 + 8)
__global__ __launch_bounds__(NTHREADS, 2)
void attn_fb(const float* __restrict__ A, const float* __restrict__ B32,
             float* __restrict__ Out) {
  __shared__ __align__(16) unsigned short Bs[BUFE];
  __shared__ float Ss[FQBLK * FSROWP];
  __shared__ unsigned short Ps[FQBLK * FPROWP];
  __shared__ float mS[FQBLK];
  __shared__ float lS[FQBLK];
  __shared__ float aS[FQBLK];

  const int tid  = threadIdx.x;
  const int wid  = tid >> 6;
  const int lane = tid & 63;
  const int l16  = lane & 15;
  const int g4   = lane >> 4;

  const int batch = blockIdx.x & 7;
  const int qt    = blockIdx.x >> 3;
  const int qbase = qt * FQBLK;

  const float* Ab   = A   + (size_t)batch * NSEQ * D;
  const float* Bb32 = B32 + (size_t)batch * NSEQ * D;
  float*       Ob   = Out + (size_t)batch * NSEQ * D;

  const float scale = 0.04419417382415922f;

  const int qi = wid >> 2;
  const int ki = wid & 3;

  const float* Arow = Ab + (size_t)(qbase + qi * 16 + l16) * D;
  bf16x8 qf[16];
  #pragma unroll
  for (int ks = 0; ks < 16; ++ks) {
    int d0 = ks * 32 + g4 * 8;
    float4 v0 = *reinterpret_cast<const float4*>(Arow + d0);
    float4 v1 = *reinterpret_cast<const float4*>(Arow + d0 + 4);
    bf16x8 f;
    f[0] = (short)f2b(v0.x * scale); f[1] = (short)f2b(v0.y * scale);
    f[2] = (short)f2b(v0.z * scale); f[3] = (short)f2b(v0.w * scale);
    f[4] = (short)f2b(v1.x * scale); f[5] = (short)f2b(v1.y * scale);
    f[6] = (short)f2b(v1.z * scale); f[7] = (short)f2b(v1.w * scale);
    qf[ks] = f;
  }
  if (tid < FQBLK) { mS[tid] = -1e30f; lS[tid] = 0.f; }

  f32x4 acc[2][4];
  #pragma unroll
  for (int mi = 0; mi < 2; ++mi)
    #pragma unroll
    for (int ni = 0; ni < 4; ++ni)
      acc[mi][ni] = (f32x4){0.f, 0.f, 0.f, 0.f};

  for (int kt = 0; kt < NT; ++kt) {
    __builtin_amdgcn_s_barrier();
    const float* Bt2 = Bb32 + (size_t)kt * KVBLK * D;
    #pragma unroll
    for (int c = 0; c < 8; ++c) {
      int id = wid * 8 + c;
      int g = id >> 2, q = id & 3;
      int kv = g * 4 + ((lane >> 1) & 3);
      int d  = q * 128 + (lane >> 3) * 16 + (lane & 1) * 8;
      const float* s = Bt2 + (size_t)kv * D + d;
      float4 v0 = *reinterpret_cast<const float4*>(s);
      float4 v1 = *reinterpret_cast<const float4*>(s + 4);
      bf16x8 h;
      h[0] = (short)f2b(v0.x); h[1] = (short)f2b(v0.y);
      h[2] = (short)f2b(v0.z); h[3] = (short)f2b(v0.w);
      h[4] = (short)f2b(v1.x); h[5] = (short)f2b(v1.y);
      h[6] = (short)f2b(v1.z); h[7] = (short)f2b(v1.w);
      *reinterpret_cast<bf16x8*>(&Bs[g * ROWE + q * 512 + lane * 8]) = h;
    }
    asm volatile("s_waitcnt lgkmcnt(0)" ::: "memory");
    __builtin_amdgcn_s_barrier();

    {
      f32x4 s = {0.f, 0.f, 0.f, 0.f};
      const int bbase = (ki * 4 + (l16 >> 2)) * ROWE + (l16 & 3) * 16 + (g4 & 1) * 8;
      #pragma unroll
      for (int ks = 0; ks < 16; ++ks) {
        const bf16x8 bf = *reinterpret_cast<const bf16x8*>(
            &Bs[bbase + (ks * 2 + (g4 >> 1)) * 64]);
        s = __builtin_amdgcn_mfma_f32_16x16x32_bf16(qf[ks], bf, s, 0, 0, 0);
      }
      #pragma unroll
      for (int r = 0; r < 4; ++r)
        Ss[(qi * 16 + g4 * 4 + r) * FSROWP + ki * 16 + l16] = s[r];
    }
    asm volatile("s_waitcnt lgkmcnt(0)" ::: "memory");
    __builtin_amdgcn_s_barrier();

    {
      int row = wid * 4 + g4;
      float sv[4];
      float mloc = -1e30f;
      #pragma unroll
      for (int j = 0; j < 4; ++j) {
        sv[j] = Ss[row * FSROWP + l16 + 16 * j];
        mloc = fmaxf(mloc, sv[j]);
      }
      #pragma unroll
      for (int off = 1; off < 16; off <<= 1)
        mloc = fmaxf(mloc, __shfl_xor(mloc, off));
      float mold = mS[row];
      float mnew = fmaxf(mold, mloc);
      float al = __expf(mold - mnew);
      float psum = 0.f;
      #pragma unroll
      for (int j = 0; j < 4; ++j) {
        float p = __expf(sv[j] - mnew);
        psum += p;
        Ps[row * FPROWP + l16 + 16 * j] = f2b(p);
      }
      #pragma unroll
      for (int off = 1; off < 16; off <<= 1)
        psum += __shfl_xor(psum, off);
      if (l16 == 0) {
        mS[row] = mnew;
        lS[row] = lS[row] * al + psum;
        aS[row] = al;
      }
    }
    asm volatile("s_waitcnt lgkmcnt(0)" ::: "memory");
    __builtin_amdgcn_s_barrier();

    {
      #pragma unroll
      for (int mi = 0; mi < 2; ++mi)
        #pragma unroll
        for (int r = 0; r < 4; ++r) {
          float a = aS[mi * 16 + g4 * 4 + r];
          #pragma unroll
          for (int ni = 0; ni < 4; ++ni)
            acc[mi][ni][r] *= a;
        }

      #pragma unroll
      for (int ks = 0; ks < 2; ++ks) {
        bf16x8 pf[2];
        #pragma unroll
        for (int mi = 0; mi < 2; ++mi)
          pf[mi] = *reinterpret_cast<const bf16x8*>(
              &Ps[(mi * 16 + l16) * FPROWP + ks * 32 + g4 * 8]);
        #pragma unroll
        for (int ni = 0; ni < 4; ++ni) {
          bf16x8 vv;
          #pragma unroll
          for (int j = 0; j < 8; ++j)
            vv[j] = (short)Bs[(ks * 8 + g4 * 2 + (j >> 2)) * ROWE
                              + (wid * 4 + ni) * 64 + (j & 3) * 16 + l16];
          #pragma unroll
          for (int mi = 0; mi < 2; ++mi)
            acc[mi][ni] = __builtin_amdgcn_mfma_f32_16x16x32_bf16(pf[mi], vv, acc[mi][ni], 0, 0, 0);
        }
      }
    }
  }

  #pragma unroll
  for (int mi = 0; mi < 2; ++mi)
    #pragma unroll
    for (int r = 0; r < 4; ++r) {
      float rl = 1.0f / lS[mi * 16 + g4 * 4 + r];
      #pragma unroll
      for (int ni = 0; ni < 4; ++ni) {
        int q = qbase + mi * 16 + g4 * 4 + r;
        int d = wid * 64 + ni * 16 + l16;
        size_t off = (size_t)q * D + d;
        Ob[off] = acc[mi][ni][r] * rl + Ab[off];
      }
    }
}

extern "C" void kernel_launch(void* const* d_in, const int* in_sizes, int n_in,
                              void* d_out, int out_size, void* d_ws, size_t ws_size,
                              hipStream_t stream) {
  const float* a = (const float*)d_in[0];
  const float* b = (const float*)d_in[1];
  float* out = (float*)d_out;
  const size_t one = (size_t)NB * NSEQ * D * sizeof(unsigned short);  // 16 MB
  dim3 block(NTHREADS);
  if (ws_size >= 2 * one) {
    unsigned short* b16 = (unsigned short*)d_ws;
    unsigned short* bT  = b16 + (size_t)NB * NSEQ * D;
    conv_dual<<<NB * 256, 256, 0, stream>>>(b, b16, bT);
    dim3 grid(NB * (NSEQ / QBLK));            // 256 blocks = 1 per CU
    attn_v13<<<grid, block, 0, stream>>>(a, b16, bT, out);
  } else {
    dim3 grid(NB * (NSEQ / FQBLK));
    attn_fb<<<grid, block, 0, stream>>>(a, b, out);
  }
}

// Round 14
// 149.360 us; speedup vs baseline: 1.4993x; 1.1345x over previous
//
#include <hip/hip_runtime.h>
#include <hip/hip_bf16.h>

#define D 512
#define NSEQ 2048
#define NB 8
#define QBLK 64
#define KVBLK 64
#define NTHREADS 512
#define NT (NSEQ / KVBLK)          // 32 kv tiles
#define ROWE 2056                  // Bs subtiled layout: elems per 4-kv-row group
#define BUFE (16 * ROWE)           // 65792 B Bs buffer
#define SROWP 68                   // f32 row stride for Ss
#define PROWP 72                   // bf16 row stride for Ps
#define CROWP 68                   // conv transpose tile stride (u16)

typedef __attribute__((ext_vector_type(8))) short bf16x8;
typedef __attribute__((ext_vector_type(4))) float f32x4;
typedef __attribute__((ext_vector_type(4))) unsigned short u16x4;

static __device__ __forceinline__ unsigned short f2b(float f) {
  unsigned u = __builtin_bit_cast(unsigned, f);
  return (unsigned short)((u + 0x7FFFu + ((u >> 16) & 1u)) >> 16);
}

// ------- conv: fp32 B -> b16 [kv][d] AND bT [d][kv] (r11-refcheck'd) --------
__global__ __launch_bounds__(256) void conv_dual(const float* __restrict__ in,
                                                 unsigned short* __restrict__ b16,
                                                 unsigned short* __restrict__ bT) {
  __shared__ unsigned short tile[64 * CROWP];
  const int bid = blockIdx.x;
  const int batch = bid >> 8;
  const int rem = bid & 255;
  const int kvt = rem >> 3;
  const int dt  = rem & 7;
  const int t = threadIdx.x;
  const int r = t >> 2;
  const int c = (t & 3) * 16;

  const float* src = in + ((size_t)batch * NSEQ + kvt * 64 + r) * D + dt * 64 + c;
  unsigned short* o16 = b16 + ((size_t)batch * NSEQ + kvt * 64 + r) * D + dt * 64 + c;

  float4 v0 = *reinterpret_cast<const float4*>(src);
  float4 v1 = *reinterpret_cast<const float4*>(src + 4);
  float4 v2 = *reinterpret_cast<const float4*>(src + 8);
  float4 v3 = *reinterpret_cast<const float4*>(src + 12);
  bf16x8 h0, h1;
  h0[0] = (short)f2b(v0.x); h0[1] = (short)f2b(v0.y);
  h0[2] = (short)f2b(v0.z); h0[3] = (short)f2b(v0.w);
  h0[4] = (short)f2b(v1.x); h0[5] = (short)f2b(v1.y);
  h0[6] = (short)f2b(v1.z); h0[7] = (short)f2b(v1.w);
  h1[0] = (short)f2b(v2.x); h1[1] = (short)f2b(v2.y);
  h1[2] = (short)f2b(v2.z); h1[3] = (short)f2b(v2.w);
  h1[4] = (short)f2b(v3.x); h1[5] = (short)f2b(v3.y);
  h1[6] = (short)f2b(v3.z); h1[7] = (short)f2b(v3.w);
  *reinterpret_cast<bf16x8*>(o16)     = h0;
  *reinterpret_cast<bf16x8*>(o16 + 8) = h1;
  #pragma unroll
  for (int i = 0; i < 4; ++i) {
    u16x4 w;
    w[0] = (unsigned short)((i < 2 ? h0 : h1)[(i & 1) * 4 + 0]);
    w[1] = (unsigned short)((i < 2 ? h0 : h1)[(i & 1) * 4 + 1]);
    w[2] = (unsigned short)((i < 2 ? h0 : h1)[(i & 1) * 4 + 2]);
    w[3] = (unsigned short)((i < 2 ? h0 : h1)[(i & 1) * 4 + 3]);
    *reinterpret_cast<u16x4*>(&tile[r * CROWP + c + i * 4]) = w;
  }
  __syncthreads();

  const int w  = t >> 6;
  const int dr = t & 63;
  unsigned short* oT = bT + (size_t)batch * D * NSEQ
                          + (size_t)(dt * 64 + dr) * NSEQ + kvt * 64 + w * 16;
  unsigned short g[16];
  #pragma unroll
  for (int i = 0; i < 16; ++i)
    g[i] = tile[(w * 16 + i) * CROWP + dr];
  bf16x8 p0, p1;
  #pragma unroll
  for (int i = 0; i < 8; ++i) { p0[i] = (short)g[i]; p1[i] = (short)g[8 + i]; }
  *reinterpret_cast<bf16x8*>(oT)     = p0;
  *reinterpret_cast<bf16x8*>(oT + 8) = p1;
}

// ---------------------------- v14 main kernel -------------------------------
// v13 post-mortem: LDS stream ~5.5K cy/tile of ~12K measured -> stalls
// dominate; the tile-end {issue 16 DMA; vmcnt(0)} exposes full L2/HBM latency
// every tile. v14 = v13 with T3/T4 counted-vmcnt schedule (pure scheduling,
// zero indexing changes):
//   Bs(kt+1) issued post-QK^T barrier  -> covered by softmax+PV
//   Bt(kt+1) issued post-PV barrier    -> covered by next QK^T+softmax
//   vmcnt(8) (never 0 mid-loop): FIFO retirement (m135) means the 8 newer
//   outstanding loads are the just-issued group; the needed group is done.
__global__ __launch_bounds__(NTHREADS, 1)
void attn_v14(const float* __restrict__ A, const unsigned short* __restrict__ B16,
              const unsigned short* __restrict__ T16, float* __restrict__ Out) {
  __shared__ __align__(16) unsigned short Bs[BUFE];          // [kv][d] subtiled
  __shared__ __align__(16) unsigned short Bt[D * KVBLK];     // [d][kv] swizzled
  __shared__ __align__(16) float Ss[QBLK * SROWP];
  __shared__ __align__(16) unsigned short Ps[QBLK * PROWP];
  __shared__ float mS[QBLK];
  __shared__ float lS[QBLK];
  __shared__ float aS[QBLK];

  const int tid  = threadIdx.x;
  const int wid  = tid >> 6;
  const int lane = tid & 63;
  const int l16  = lane & 15;
  const int g4   = lane >> 4;

  const int batch = blockIdx.x & 7;       // batch -> XCD (L2 locality)
  const int qt    = blockIdx.x >> 3;      // 0..31
  const int qbase = qt * QBLK;

  const float*          Ab = A   + (size_t)batch * NSEQ * D;
  const unsigned short* Kb = B16 + (size_t)batch * NSEQ * D;
  const unsigned short* Tb = T16 + (size_t)batch * D * NSEQ;
  float*                Ob = Out + (size_t)batch * NSEQ * D;

  const float scale = 0.04419417382415922f;  // 1/sqrt(512)

  const int qi = wid >> 1;   // wave's q 16-tile (0..3)
  const int kp = wid & 1;    // wave's kv pair: kv-tiles kp*2, kp*2+1

  // ---- Q tile into registers (pre-scaled), v4/v5-verified pattern ----
  const float* Arow = Ab + (size_t)(qbase + qi * 16 + l16) * D;
  bf16x8 qf[16];
  #pragma unroll
  for (int ks = 0; ks < 16; ++ks) {
    int d0 = ks * 32 + g4 * 8;
    float4 v0 = *reinterpret_cast<const float4*>(Arow + d0);
    float4 v1 = *reinterpret_cast<const float4*>(Arow + d0 + 4);
    bf16x8 f;
    f[0] = (short)f2b(v0.x * scale); f[1] = (short)f2b(v0.y * scale);
    f[2] = (short)f2b(v0.z * scale); f[3] = (short)f2b(v0.w * scale);
    f[4] = (short)f2b(v1.x * scale); f[5] = (short)f2b(v1.y * scale);
    f[6] = (short)f2b(v1.z * scale); f[7] = (short)f2b(v1.w * scale);
    qf[ks] = f;
  }
  if (tid < QBLK) { mS[tid] = -1e30f; lS[tid] = 0.f; }

  f32x4 acc[4][4];
  #pragma unroll
  for (int mi = 0; mi < 4; ++mi)
    #pragma unroll
    for (int ni = 0; ni < 4; ++ni)
      acc[mi][ni] = (f32x4){0.f, 0.f, 0.f, 0.f};

  // ---- prologue: DMA Bs(0) + Bt(0), full drain ----
  #pragma unroll
  for (int c = 0; c < 8; ++c) {
    int id = wid * 8 + c;
    int g = id >> 2, q = id & 3;
    const unsigned short* src = Kb
        + (size_t)(g * 4 + ((lane >> 1) & 3)) * D
        + q * 128 + (lane >> 3) * 16 + (lane & 1) * 8;
    unsigned short* dst = &Bs[g * ROWE + q * 512];
    __builtin_amdgcn_global_load_lds(
        (const __attribute__((address_space(1))) void*)src,
        (__attribute__((address_space(3))) void*)dst, 16, 0, 0);
  }
  #pragma unroll
  for (int c = 0; c < 8; ++c) {
    int drow = wid * 64 + c * 8 + (lane >> 3);
    int chunk = (lane & 7) ^ ((lane >> 3) & 7);
    const unsigned short* src = Tb + (size_t)drow * NSEQ + chunk * 8;
    unsigned short* dst = (unsigned short*)&Bt[(wid * 64 + c * 8) * KVBLK];
    __builtin_amdgcn_global_load_lds(
        (const __attribute__((address_space(1))) void*)src,
        (__attribute__((address_space(3))) void*)dst, 16, 0, 0);
  }
  asm volatile("s_waitcnt vmcnt(0)" ::: "memory");
  asm volatile("s_waitcnt lgkmcnt(0)" ::: "memory");
  __builtin_amdgcn_s_barrier();

  const int bbase0 = ((kp * 2) * 4 + (l16 >> 2)) * ROWE + (l16 & 3) * 16 + (g4 & 1) * 8;
  const int bbase1 = bbase0 + 4 * ROWE;   // next kv 16-tile (+16 kv rows)

  for (int kt = 0; kt < NT; ++kt) {
    // ---- QK^T: Q from regs, B from Bs (b128); 2 kv-tiles per wave ----
    {
      f32x4 s0 = {0.f, 0.f, 0.f, 0.f};
      f32x4 s1 = {0.f, 0.f, 0.f, 0.f};
      __builtin_amdgcn_s_setprio(1);
      #pragma unroll
      for (int ks = 0; ks < 16; ++ks) {
        const int ro = (ks * 2 + (g4 >> 1)) * 64;
        const bf16x8 b0 = *reinterpret_cast<const bf16x8*>(&Bs[bbase0 + ro]);
        const bf16x8 b1 = *reinterpret_cast<const bf16x8*>(&Bs[bbase1 + ro]);
        s0 = __builtin_amdgcn_mfma_f32_16x16x32_bf16(qf[ks], b0, s0, 0, 0, 0);
        s1 = __builtin_amdgcn_mfma_f32_16x16x32_bf16(qf[ks], b1, s1, 0, 0, 0);
      }
      __builtin_amdgcn_s_setprio(0);
      #pragma unroll
      for (int r = 0; r < 4; ++r) {
        Ss[(qi * 16 + g4 * 4 + r) * SROWP + (kp * 2) * 16 + l16]     = s0[r];
        Ss[(qi * 16 + g4 * 4 + r) * SROWP + (kp * 2 + 1) * 16 + l16] = s1[r];
      }
    }
    asm volatile("s_waitcnt lgkmcnt(0)" ::: "memory");
    __builtin_amdgcn_s_barrier();                       // A: Ss visible; Bs reads done

    // ---- issue Bs(kt+1): lands under softmax + PV ----
    if (kt + 1 < NT) {
      const unsigned short* Kt = Kb + (size_t)(kt + 1) * KVBLK * D;
      #pragma unroll
      for (int c = 0; c < 8; ++c) {
        int id = wid * 8 + c;
        int g = id >> 2, q = id & 3;
        const unsigned short* src = Kt
            + (size_t)(g * 4 + ((lane >> 1) & 3)) * D
            + q * 128 + (lane >> 3) * 16 + (lane & 1) * 8;
        unsigned short* dst = &Bs[g * ROWE + q * 512];
        __builtin_amdgcn_global_load_lds(
            (const __attribute__((address_space(1))) void*)src,
            (__attribute__((address_space(3))) void*)dst, 16, 0, 0);
      }
    }

    // ---- online softmax: 8 lanes/row, strided cols (r12-verified) ----
    {
      int row = wid * 8 + (lane >> 3);
      int c   = lane & 7;
      float sv[8];
      float mloc = -1e30f;
      #pragma unroll
      for (int j = 0; j < 8; ++j) {
        sv[j] = Ss[row * SROWP + c + 8 * j];   // bank = 4r+c+8j -> <=2-way
        mloc = fmaxf(mloc, sv[j]);
      }
      #pragma unroll
      for (int off = 1; off < 8; off <<= 1)
        mloc = fmaxf(mloc, __shfl_xor(mloc, off));
      float mold = mS[row];
      float mnew = fmaxf(mold, mloc);
      float al = __expf(mold - mnew);
      float psum = 0.f;
      #pragma unroll
      for (int j = 0; j < 8; ++j) {
        float p = __expf(sv[j] - mnew);
        psum += p;
        Ps[row * PROWP + c + 8 * j] = f2b(p);  // strided u16: 2 lanes/bank
      }
      #pragma unroll
      for (int off = 1; off < 8; off <<= 1)
        psum += __shfl_xor(psum, off);
      if (c == 0) {
        mS[row] = mnew;
        lS[row] = lS[row] * al + psum;
        aS[row] = al;
      }
    }
    asm volatile("s_waitcnt lgkmcnt(0)" ::: "memory");
    // Bt(kt) must be landed before PV. Outstanding: Bt(kt) [<=8] + Bs(kt+1) [8 if issued].
    if (kt + 1 < NT) {
      asm volatile("s_waitcnt vmcnt(8)" ::: "memory");
    } else {
      asm volatile("s_waitcnt vmcnt(0)" ::: "memory");
    }
    __builtin_amdgcn_s_barrier();                       // B: Ps + Bt(kt) ready

    // ---- rescale (col = q = l16) + PV: O^T += V^T * P^T (r11 verbatim) ----
    {
      #pragma unroll
      for (int mi = 0; mi < 4; ++mi) {
        float a = aS[mi * 16 + l16];
        #pragma unroll
        for (int ni = 0; ni < 4; ++ni)
          #pragma unroll
          for (int r = 0; r < 4; ++r)
            acc[mi][ni][r] *= a;
      }

      const char* Bc = (const char*)&Bt[0];
      __builtin_amdgcn_s_setprio(1);
      #pragma unroll
      for (int ks = 0; ks < 2; ++ks) {
        bf16x8 pf[4];
        #pragma unroll
        for (int mi = 0; mi < 4; ++mi)
          pf[mi] = *reinterpret_cast<const bf16x8*>(
              &Ps[(mi * 16 + l16) * PROWP + ks * 32 + g4 * 8]);
        #pragma unroll
        for (int ni = 0; ni < 4; ++ni) {
          int row = wid * 64 + ni * 16 + l16;
          int swz = (ks * 4 + g4) ^ (l16 & 7);
          const bf16x8 vf = *reinterpret_cast<const bf16x8*>(Bc + row * 128 + swz * 16);
          #pragma unroll
          for (int mi = 0; mi < 4; ++mi)
            acc[mi][ni] = __builtin_amdgcn_mfma_f32_16x16x32_bf16(vf, pf[mi], acc[mi][ni], 0, 0, 0);
        }
      }
      __builtin_amdgcn_s_setprio(0);
    }
    asm volatile("s_waitcnt lgkmcnt(0)" ::: "memory");
    __builtin_amdgcn_s_barrier();                       // C: Bt reads done

    // ---- issue Bt(kt+1); wait Bs(kt+1) landed (oldest 8 of 16) ----
    if (kt + 1 < NT) {
      #pragma unroll
      for (int c = 0; c < 8; ++c) {
        int drow = wid * 64 + c * 8 + (lane >> 3);
        int chunk = (lane & 7) ^ ((lane >> 3) & 7);
        const unsigned short* src = Tb + (size_t)drow * NSEQ + (kt + 1) * KVBLK + chunk * 8;
        unsigned short* dst = (unsigned short*)&Bt[(wid * 64 + c * 8) * KVBLK];
        __builtin_amdgcn_global_load_lds(
            (const __attribute__((address_space(1))) void*)src,
            (__attribute__((address_space(3))) void*)dst, 16, 0, 0);
      }
      asm volatile("s_waitcnt vmcnt(8)" ::: "memory");
    }
    __builtin_amdgcn_s_barrier();                       // D: Bs(kt+1) ready
  }

  // ---- epilogue: Out[q][d] = accT/l + A[q][d] (r11 verbatim) ----
  #pragma unroll
  for (int mi = 0; mi < 4; ++mi) {
    float rl = 1.0f / lS[mi * 16 + l16];
    int q = qbase + mi * 16 + l16;
    #pragma unroll
    for (int ni = 0; ni < 4; ++ni) {
      int d = wid * 64 + ni * 16 + g4 * 4;
      const float4 av = *reinterpret_cast<const float4*>(Ab + (size_t)q * D + d);
      float4 o;
      o.x = acc[mi][ni][0] * rl + av.x;
      o.y = acc[mi][ni][1] * rl + av.y;
      o.z = acc[mi][ni][2] * rl + av.z;
      o.w = acc[mi][ni][3] * rl + av.w;
      *reinterpret_cast<float4*>(Ob + (size_t)q * D + d) = o;
    }
  }
}

// ---------- fallback: in-kernel convert staging (no workspace) --------------
#define FQBLK 32
#define FSROWP (64 + 4)
#define FPROWP (64 + 8)
__global__ __launch_bounds__(NTHREADS, 2)
void attn_fb(const float* __restrict__ A, const float* __restrict__ B32,
             float* __restrict__ Out) {
  __shared__ __align__(16) unsigned short Bs[BUFE];
  __shared__ float Ss[FQBLK * FSROWP];
  __shared__ unsigned short Ps[FQBLK * FPROWP];
  __shared__ float mS[FQBLK];
  __shared__ float lS[FQBLK];
  __shared__ float aS[FQBLK];

  const int tid  = threadIdx.x;
  const int wid  = tid >> 6;
  const int lane = tid & 63;
  const int l16  = lane & 15;
  const int g4   = lane >> 4;

  const int batch = blockIdx.x & 7;
  const int qt    = blockIdx.x >> 3;
  const int qbase = qt * FQBLK;

  const float* Ab   = A   + (size_t)batch * NSEQ * D;
  const float* Bb32 = B32 + (size_t)batch * NSEQ * D;
  float*       Ob   = Out + (size_t)batch * NSEQ * D;

  const float scale = 0.04419417382415922f;

  const int qi = wid >> 2;
  const int ki = wid & 3;

  const float* Arow = Ab + (size_t)(qbase + qi * 16 + l16) * D;
  bf16x8 qf[16];
  #pragma unroll
  for (int ks = 0; ks < 16; ++ks) {
    int d0 = ks * 32 + g4 * 8;
    float4 v0 = *reinterpret_cast<const float4*>(Arow + d0);
    float4 v1 = *reinterpret_cast<const float4*>(Arow + d0 + 4);
    bf16x8 f;
    f[0] = (short)f2b(v0.x * scale); f[1] = (short)f2b(v0.y * scale);
    f[2] = (short)f2b(v0.z * scale); f[3] = (short)f2b(v0.w * scale);
    f[4] = (short)f2b(v1.x * scale); f[5] = (short)f2b(v1.y * scale);
    f[6] = (short)f2b(v1.z * scale); f[7] = (short)f2b(v1.w * scale);
    qf[ks] = f;
  }
  if (tid < FQBLK) { mS[tid] = -1e30f; lS[tid] = 0.f; }

  f32x4 acc[2][4];
  #pragma unroll
  for (int mi = 0; mi < 2; ++mi)
    #pragma unroll
    for (int ni = 0; ni < 4; ++ni)
      acc[mi][ni] = (f32x4){0.f, 0.f, 0.f, 0.f};

  for (int kt = 0; kt < NT; ++kt) {
    __builtin_amdgcn_s_barrier();
    const float* Bt2 = Bb32 + (size_t)kt * KVBLK * D;
    #pragma unroll
    for (int c = 0; c < 8; ++c) {
      int id = wid * 8 + c;
      int g = id >> 2, q = id & 3;
      int kv = g * 4 + ((lane >> 1) & 3);
      int d  = q * 128 + (lane >> 3) * 16 + (lane & 1) * 8;
      const float* s = Bt2 + (size_t)kv * D + d;
      float4 v0 = *reinterpret_cast<const float4*>(s);
      float4 v1 = *reinterpret_cast<const float4*>(s + 4);
      bf16x8 h;
      h[0] = (short)f2b(v0.x); h[1] = (short)f2b(v0.y);
      h[2] = (short)f2b(v0.z); h[3] = (short)f2b(v0.w);
      h[4] = (short)f2b(v1.x); h[5] = (short)f2b(v1.y);
      h[6] = (short)f2b(v1.z); h[7] = (short)f2b(v1.w);
      *reinterpret_cast<bf16x8*>(&Bs[g * ROWE + q * 512 + lane * 8]) = h;
    }
    asm volatile("s_waitcnt lgkmcnt(0)" ::: "memory");
    __builtin_amdgcn_s_barrier();

    {
      f32x4 s = {0.f, 0.f, 0.f, 0.f};
      const int bbase = (ki * 4 + (l16 >> 2)) * ROWE + (l16 & 3) * 16 + (g4 & 1) * 8;
      #pragma unroll
      for (int ks = 0; ks < 16; ++ks) {
        const bf16x8 bf = *reinterpret_cast<const bf16x8*>(
            &Bs[bbase + (ks * 2 + (g4 >> 1)) * 64]);
        s = __builtin_amdgcn_mfma_f32_16x16x32_bf16(qf[ks], bf, s, 0, 0, 0);
      }
      #pragma unroll
      for (int r = 0; r < 4; ++r)
        Ss[(qi * 16 + g4 * 4 + r) * FSROWP + ki * 16 + l16] = s[r];
    }
    asm volatile("s_waitcnt lgkmcnt(0)" ::: "memory");
    __builtin_amdgcn_s_barrier();

    {
      int row = wid * 4 + g4;
      float sv[4];
      float mloc = -1e30f;
      #pragma unroll
      for (int j = 0; j < 4; ++j) {
        sv[j] = Ss[row * FSROWP + l16 + 16 * j];
        mloc = fmaxf(mloc, sv[j]);
      }
      #pragma unroll
      for (int off = 1; off < 16; off <<= 1)
        mloc = fmaxf(mloc, __shfl_xor(mloc, off));
      float mold = mS[row];
      float mnew = fmaxf(mold, mloc);
      float al = __expf(mold - mnew);
      float psum = 0.f;
      #pragma unroll
      for (int j = 0; j < 4; ++j) {
        float p = __expf(sv[j] - mnew);
        psum += p;
        Ps[row * FPROWP + l16 + 16 * j] = f2b(p);
      }
      #pragma unroll
      for (int off = 1; off < 16; off <<= 1)
        psum += __shfl_xor(psum, off);
      if (l16 == 0) {
        mS[row] = mnew;
        lS[row] = lS[row] * al + psum;
        aS[row] = al;
      }
    }
    asm volatile("s_waitcnt lgkmcnt(0)" ::: "memory");
    __builtin_amdgcn_s_barrier();

    {
      #pragma unroll
      for (int mi = 0; mi < 2; ++mi)
        #pragma unroll
        for (int r = 0; r < 4; ++r) {
          float a = aS[mi * 16 + g4 * 4 + r];
          #pragma unroll
          for (int ni = 0; ni < 4; ++ni)
            acc[mi][ni][r] *= a;
        }

      #pragma unroll
      for (int ks = 0; ks < 2; ++ks) {
        bf16x8 pf[2];
        #pragma unroll
        for (int mi = 0; mi < 2; ++mi)
          pf[mi] = *reinterpret_cast<const bf16x8*>(
              &Ps[(mi * 16 + l16) * FPROWP + ks * 32 + g4 * 8]);
        #pragma unroll
        for (int ni = 0; ni < 4; ++ni) {
          bf16x8 vv;
          #pragma unroll
          for (int j = 0; j < 8; ++j)
            vv[j] = (short)Bs[(ks * 8 + g4 * 2 + (j >> 2)) * ROWE
                              + (wid * 4 + ni) * 64 + (j & 3) * 16 + l16];
          #pragma unroll
          for (int mi = 0; mi < 2; ++mi)
            acc[mi][ni] = __builtin_amdgcn_mfma_f32_16x16x32_bf16(pf[mi], vv, acc[mi][ni], 0, 0, 0);
        }
      }
    }
  }

  #pragma unroll
  for (int mi = 0; mi < 2; ++mi)
    #pragma unroll
    for (int r = 0; r < 4; ++r) {
      float rl = 1.0f / lS[mi * 16 + g4 * 4 + r];
      #pragma unroll
      for (int ni = 0; ni < 4; ++ni) {
        int q = qbase + mi * 16 + g4 * 4 + r;
        int d = wid * 64 + ni * 16 + l16;
        size_t off = (size_t)q * D + d;
        Ob[off] = acc[mi][ni][r] * rl + Ab[off];
      }
    }
}

extern "C" void kernel_launch(void* const* d_in, const int* in_sizes, int n_in,
                              void* d_out, int out_size, void* d_ws, size_t ws_size,
                              hipStream_t stream) {
  const float* a = (const float*)d_in[0];
  const float* b = (const float*)d_in[1];
  float* out = (float*)d_out;
  const size_t one = (size_t)NB * NSEQ * D * sizeof(unsigned short);  // 16 MB
  dim3 block(NTHREADS);
  if (ws_size >= 2 * one) {
    unsigned short* b16 = (unsigned short*)d_ws;
    unsigned short* bT  = b16 + (size_t)NB * NSEQ * D;
    conv_dual<<<NB * 256, 256, 0, stream>>>(b, b16, bT);
    dim3 grid(NB * (NSEQ / QBLK));            // 256 blocks = 1 per CU
    attn_v14<<<grid, block, 0, stream>>>(a, b16, bT, out);
  } else {
    dim3 grid(NB * (NSEQ / FQBLK));
    attn_fb<<<grid, block, 0, stream>>>(a, b, out);
  }
}